// Round 4
// baseline (178.008 us; speedup 1.0000x reference)
//
#include <hip/hip_runtime.h>
#include <hip/hip_bf16.h>

// MultiHead attention, MI355X/gfx950. fp32 in/out, bf16 MFMA internals.
// B=2, T=2048, C=1024, H=16, D=64.
// Round 11: attn = R8 schedule (single __syncthreads dbuf -- R10's counted
// vmcnt 3-buf REGRESSED 33->40us) with r=32 q-rows/wave at FULL wave count:
// 1024 blocks x 2 waves x 32 rows = 2048 waves (2/SIMD), one 64-row chunk
// per block, trip = mt+1. LDS-read volume halves vs r=16 (volume ~ 1/r:
// each wave reads the full 16KB tile per k-tile regardless of rows owned).
// Imbalance handled by LPT: mt = 31-(fid>>5), longest blocks first, short
// ones backfill the tail. R9 lesson: r=32 with halves-pairing halved waves
// -> 1/SIMD collapse; this keeps 2048 waves.
//
// ws layout (bf16 elems):
//   xb  [4096][1024]            @ 0          (x as bf16)
//   wt  [3][16][64][1024]       @ 4194304    (= fused Bt [3072][1024])
//   wot [1024][1024]            @ 7340032    (Wo transposed, bf16)
//   qkv Q,K:[h][b*2048+t][d] Vt:[h][b][d][t] @ 8388608  (Q pre-scaled log2e/32)
//   att [4096][1024]            @ 20971520
// total 25165824 elems = 48 MB

typedef __hip_bfloat16 bf16;
typedef __bf16 v8bf __attribute__((ext_vector_type(8)));
typedef float  v4f  __attribute__((ext_vector_type(4)));
typedef unsigned long long u64;
typedef unsigned int u32;

#define MFMA16(a, b, c) __builtin_amdgcn_mfma_f32_16x16x32_bf16((a), (b), (c), 0, 0, 0)

__device__ __forceinline__ bf16 f2b(float x) { return __float2bfloat16(x); }
__device__ __forceinline__ __bf16 f2braw(float x) {
  bf16 t = __float2bfloat16(x);
  return *reinterpret_cast<__bf16*>(&t);
}
__device__ __forceinline__ unsigned short f2bu(float x) {
  bf16 t = __float2bfloat16(x);
  return *reinterpret_cast<unsigned short*>(&t);
}

// async global->LDS, 16B per lane; LDS dest = wave-uniform base + lane*16.
__device__ __forceinline__ void load16_lds(const bf16* gptr, const bf16* lptr) {
  __builtin_amdgcn_global_load_lds(
      (const __attribute__((address_space(1))) u32*)gptr,
      (__attribute__((address_space(3))) u32*)lptr, 16, 0, 0);
}

// ---------------------------------------------------------------------------
// Fused prep: [0,2048) cvt_x | [2048,5120) Wq/Wk/Wv transpose | [5120,6144) Wo.
// ---------------------------------------------------------------------------
__global__ __launch_bounds__(256) void prep_kernel(
    const float* __restrict__ x,
    const float* __restrict__ Wq, const float* __restrict__ Wk,
    const float* __restrict__ Wv, const float* __restrict__ Wo,
    bf16* __restrict__ xb, bf16* __restrict__ wt, bf16* __restrict__ wot)
{
  __shared__ float Lt[32][33];
  const int bid = blockIdx.x, tid = threadIdx.x;

  if (bid < 2048) {                        // x fp32 -> bf16
    size_t i = ((size_t)bid * 256 + tid) * 8;
    float4 f0 = *(const float4*)(x + i);
    float4 f1 = *(const float4*)(x + i + 4);
    v8bf v;
    v[0] = f2braw(f0.x); v[1] = f2braw(f0.y); v[2] = f2braw(f0.z); v[3] = f2braw(f0.w);
    v[4] = f2braw(f1.x); v[5] = f2braw(f1.y); v[6] = f2braw(f1.z); v[7] = f2braw(f1.w);
    *(v8bf*)(xb + i) = v;
    return;
  }
  const int tx = tid & 31, ty = tid >> 5;
  if (bid < 5120) {                        // Wq/Wk/Wv [h][1024][64] -> wt [z][64][1024]
    const int idx = bid - 2048;
    const int z = idx >> 6, rem = idx & 63;
    const int p = z >> 4, h = z & 15;
    const float* ib = ((p == 0) ? Wq : (p == 1) ? Wk : Wv) + (size_t)h * 65536;
    bf16* ob = wt + (size_t)z * 65536;
    const int j0 = (rem & 1) * 32, i0 = (rem >> 1) * 32;
    #pragma unroll
    for (int r = 0; r < 4; ++r)
      Lt[ty + 8 * r][tx] = ib[(size_t)(i0 + ty + 8 * r) * 64 + j0 + tx];
    __syncthreads();
    #pragma unroll
    for (int r = 0; r < 4; ++r)
      ob[(size_t)(j0 + ty + 8 * r) * 1024 + i0 + tx] = f2b(Lt[tx][ty + 8 * r]);
  } else {                                 // Wo [1024][1024] -> wot transposed
    const int idx = bid - 5120;
    const int j0 = (idx & 31) * 32, i0 = (idx >> 5) * 32;
    #pragma unroll
    for (int r = 0; r < 4; ++r)
      Lt[ty + 8 * r][tx] = Wo[(size_t)(i0 + ty + 8 * r) * 1024 + j0 + tx];
    __syncthreads();
    #pragma unroll
    for (int r = 0; r < 4; ++r)
      wot[(size_t)(j0 + ty + 8 * r) * 1024 + i0 + tx] = f2b(Lt[tx][ty + 8 * r]);
  }
}

// ---------------------------------------------------------------------------
// Kernel 1: fused QKV GEMM, M=4096 x N=3072, K=1024. 128x128 tile, BK=32,
// double-buffered LDS, ONE barrier per k-step. grid (32 mt, 24 nt).
// Epilogue scatters Q,K ([h][m][d], Q*log2e/32) and V transposed
// ([h][b][d][t]).
// ---------------------------------------------------------------------------
__global__ __launch_bounds__(256) void qkv_gemm_kernel(
    const bf16* __restrict__ xb, const bf16* __restrict__ wt,
    bf16* __restrict__ qkv)
{
  __shared__ __align__(16) bf16 Ash[2][128][32];
  __shared__ __align__(16) bf16 Bsh[2][128][32];

  const int mt = blockIdx.x, nt = blockIdx.y;
  const int tid = threadIdx.x, w = tid >> 6, lane = tid & 63;
  const int ln = lane & 15, quad = lane >> 4;
  const int wm = w >> 1, wn = w & 1;
  const int m0 = mt * 128, n0 = nt * 128;

  const v4f vzero = {0.f, 0.f, 0.f, 0.f};
  v4f acc[4][4];
  #pragma unroll
  for (int mf = 0; mf < 4; ++mf)
    #pragma unroll
    for (int nf = 0; nf < 4; ++nf) acc[mf][nf] = vzero;

  const int srow = lane >> 2, sseg = (lane & 3) * 8;
  const bf16* ga = xb + (size_t)(m0 + 32 * w + srow) * 1024 + sseg;
  const bf16* gb = wt + (size_t)(n0 + 32 * w + srow) * 1024 + sseg;

  // prologue: stage k-step 0 into buf 0
  {
    load16_lds(ga,             &Ash[0][32 * w][0]);
    load16_lds(ga + 16 * 1024, &Ash[0][32 * w + 16][0]);
    load16_lds(gb,             &Bsh[0][32 * w][0]);
    load16_lds(gb + 16 * 1024, &Bsh[0][32 * w + 16][0]);
  }

  for (int kt = 0; kt < 32; ++kt) {
    const int buf = kt & 1;
    __syncthreads();                       // publishes buf (drains loads)

    v8bf af[4], bfv[4];
    #pragma unroll
    for (int mf = 0; mf < 4; ++mf)
      af[mf] = *(const v8bf*)&Ash[buf][wm * 64 + mf * 16 + ln][quad * 8];
    #pragma unroll
    for (int nf = 0; nf < 4; ++nf)
      bfv[nf] = *(const v8bf*)&Bsh[buf][wn * 64 + nf * 16 + ln][quad * 8];

    if (kt < 31) {                         // stage kt+1 into other buffer
      const int k0 = (kt + 1) * 32, nb = buf ^ 1;
      load16_lds(ga + k0,             &Ash[nb][32 * w][0]);
      load16_lds(ga + 16 * 1024 + k0, &Ash[nb][32 * w + 16][0]);
      load16_lds(gb + k0,             &Bsh[nb][32 * w][0]);
      load16_lds(gb + 16 * 1024 + k0, &Bsh[nb][32 * w + 16][0]);
    }

    #pragma unroll
    for (int mf = 0; mf < 4; ++mf)
      #pragma unroll
      for (int nf = 0; nf < 4; ++nf)
        acc[mf][nf] = MFMA16(af[mf], bfv[nf], acc[mf][nf]);
  }

  const int jcol0 = n0 + wn * 64;
  const int p = jcol0 >> 10;
  const int h = (jcol0 >> 6) & 15;
  // Q pre-scale: (1/sqrt(1024)) * log2(e), so attn can use exp2 directly.
  const float scale = (p == 0) ? 0.0450841149f : 1.0f;

  if (p < 2) {                               // Q, K: [h][m][d]
    bf16* base = qkv + (size_t)p * 4194304 + (size_t)h * 262144;
    #pragma unroll
    for (int mf = 0; mf < 4; ++mf)
      #pragma unroll
      for (int nf = 0; nf < 4; ++nf) {
        int d = nf * 16 + ln;
        #pragma unroll
        for (int r = 0; r < 4; ++r) {
          int m = m0 + wm * 64 + mf * 16 + quad * 4 + r;
          base[(size_t)m * 64 + d] = f2b(acc[mf][nf][r] * scale);
        }
      }
  } else {                                   // V transposed: [h][b][d][t]
    bf16* vb = qkv + (size_t)2 * 4194304 + (size_t)h * 262144;
    #pragma unroll
    for (int mf = 0; mf < 4; ++mf) {
      int mrow = m0 + wm * 64 + mf * 16 + quad * 4;
      int bi = mrow >> 11, t0 = mrow & 2047;
      #pragma unroll
      for (int nf = 0; nf < 4; ++nf) {
        int d = nf * 16 + ln;
        u64 pk = (u64)f2bu(acc[mf][nf][0]) |
                 ((u64)f2bu(acc[mf][nf][1]) << 16) |
                 ((u64)f2bu(acc[mf][nf][2]) << 32) |
                 ((u64)f2bu(acc[mf][nf][3]) << 48);
        *(u64*)(vb + (size_t)bi * 131072 + (size_t)d * 2048 + t0) = pk;
      }
    }
  }
}

// ---------------------------------------------------------------------------
// Kernel 2: causal flash attention, swapped-QK^T in-register softmax.
// Block = 2 waves x 32 q-rows = one 64-row chunk; trip = mt+1 k-tiles.
// LPT order: mt = 31-(fid>>5) (longest first, short blocks backfill tail).
// grid 1024 = 2048 waves = 2/SIMD. Single-__syncthreads dbuf (R8 schedule).
// Each wave owns 32 q-rows (mc in {0,1}); full 16KB K/V tile fragment reads
// shared across both mc halves -> LDS volume halved vs r=16.
// K staged row-PERMUTED (kperm) so S^T = mfma(K,Q) lanes, after exp2, are
// byte-exact A-fragments for PV. K/V LDS XOR slot-swizzled via pre-swizzled
// global source addrs. Row-sum via mfma(pa, ones). T5 setprio around MFMA.
// grp = fid&31 so same-(b,h) blocks share an XCD (K/V 512KB/(b,h) in L2).
// ---------------------------------------------------------------------------
__global__ __launch_bounds__(128, 2) void attn_kernel(
    const bf16* __restrict__ qkv, bf16* __restrict__ att)
{
  __shared__ __align__(16) bf16 Ksh[2][64][64];   // [buf][perm-row][d, slot-swz]
  __shared__ __align__(16) bf16 Vsh[2][64][64];   // [buf][d][t', slot-swz]

  const int fid = blockIdx.x;              // 0..1023
  const int mt = 31 - (fid >> 5);          // descending chunk = LPT schedule
  const int grp = fid & 31;                // fid%8 == grp%8 -> same-grp same XCD
  const int b = grp >> 4, h = grp & 15;

  const int tid = threadIdx.x, w = tid >> 6, lane = tid & 63;
  const int ln = lane & 15, quad = lane >> 4;

  const bf16* qbase  = qkv + (size_t)h * 262144 + (size_t)b * 131072;
  const bf16* kbase  = qbase + 4194304;
  const bf16* vtbase = qbase + 8388608;    // [d][t], d-stride 2048

  // ---- staging lane constants (wave w stages LDS rows w*32..w*32+31) ----
  const int l8 = lane & 7, r8 = lane >> 3;
  const int slot = l8 ^ r8;                // swizzle: LDS[row][s] = G[row][s^(row&7)]
  // kperm(p): LDS row p holds K row (p&32) | ((p&12)<<1) | ((p&16)>>2) | (p&3)
  const bf16* gk[4];
  const bf16* gv[4];
  #pragma unroll
  for (int i = 0; i < 4; ++i) {
    const int p = w * 32 + 8 * i + r8;
    const int kp = (p & 32) | ((p & 12) << 1) | ((p & 16) >> 2) | (p & 3);
    gk[i] = kbase + kp * 64 + slot * 8;
    gv[i] = vtbase + p * 2048 + slot * 8;
  }

  // ---- fragment-read lane constants (element offsets into [64][64]) ----
  const int sw = ln & 7;
  const int c0 = ((quad    ) ^ sw) * 8;    // ks=0: global slot quad
  const int c1 = ((quad + 4) ^ sw) * 8;    // ks=1: global slot 4+quad
  const int rowoff = ln * 64;

  v8bf vone;
  {
    unsigned short u = 0x3F80;             // 1.0 bf16
    __bf16 e = *reinterpret_cast<__bf16*>(&u);
    #pragma unroll
    for (int j = 0; j < 8; ++j) vone[j] = e;
  }
  const v4f vzero = {0.f, 0.f, 0.f, 0.f};
  const float NEG = -30000.0f;

  #define STAGE(KB, BUF) {                                       \
    load16_lds(gk[0] + (KB) * 4096, &Ksh[BUF][w * 32][0]);       \
    load16_lds(gk[1] + (KB) * 4096, &Ksh[BUF][w * 32 + 8][0]);   \
    load16_lds(gk[2] + (KB) * 4096, &Ksh[BUF][w * 32 + 16][0]);  \
    load16_lds(gk[3] + (KB) * 4096, &Ksh[BUF][w * 32 + 24][0]);  \
    load16_lds(gv[0] + (KB) * 64,   &Vsh[BUF][w * 32][0]);       \
    load16_lds(gv[1] + (KB) * 64,   &Vsh[BUF][w * 32 + 8][0]);   \
    load16_lds(gv[2] + (KB) * 64,   &Vsh[BUF][w * 32 + 16][0]);  \
    load16_lds(gv[3] + (KB) * 64,   &Vsh[BUF][w * 32 + 24][0]); }

  const int wrow = mt * 64 + w * 32;       // wave's q rows: wrow..wrow+31

  // Q fragments (B-operand): Q[wrow+mc*16+ln][ks*32 + quad*8 + j]
  v8bf aq[2][2];
  #pragma unroll
  for (int mc = 0; mc < 2; ++mc)
    #pragma unroll
    for (int ks = 0; ks < 2; ++ks)
      aq[mc][ks] = *(const v8bf*)(qbase +
          (size_t)(wrow + mc * 16 + ln) * 64 + ks * 32 + quad * 8);

  v4f o[2][4], lacc[2];
  #pragma unroll
  for (int mc = 0; mc < 2; ++mc) {
    lacc[mc] = vzero;
    #pragma unroll
    for (int dt = 0; dt < 4; ++dt) o[mc][dt] = vzero;
  }

  STAGE(0, 0)

  const int kb_end = mt;
  for (int kb = 0; kb <= kb_end; ++kb) {
    const int buf = kb & 1;
    __syncthreads();                       // publishes buf (drains loads)

    v8bf kf[2][4], vf[2][4];
    const bf16* kr = &Ksh[buf][0][0];
    const bf16* vr = &Vsh[buf][0][0];
    #pragma unroll
    for (int nf = 0; nf < 4; ++nf) {
      kf[0][nf] = *(const v8bf*)(kr + nf * 1024 + rowoff + c0);
      kf[1][nf] = *(const v8bf*)(kr + nf * 1024 + rowoff + c1);
      vf[0][nf] = *(const v8bf*)(vr + nf * 1024 + rowoff + c0);
      vf[1][nf] = *(const v8bf*)(vr + nf * 1024 + rowoff + c1);
    }

    if (kb < kb_end) STAGE(kb + 1, buf ^ 1)

    #pragma unroll
    for (int mc = 0; mc < 2; ++mc) {
      // S^T = K . Q^T : D[m = perm'd k][n = q(ln)]
      __builtin_amdgcn_s_setprio(1);
      v4f s[4];
      #pragma unroll
      for (int nf = 0; nf < 4; ++nf) s[nf] = vzero;
      #pragma unroll
      for (int ks = 0; ks < 2; ++ks)
        #pragma unroll
        for (int nf = 0; nf < 4; ++nf)
          s[nf] = MFMA16(kf[ks][nf], aq[mc][ks], s[nf]);
      __builtin_amdgcn_s_setprio(0);

      const int qg = wrow + mc * 16 + ln;
      if (kb == kb_end) {                  // causal mask (diagonal tile)
        #pragma unroll
        for (int nf = 0; nf < 4; ++nf) {
          const int kc = kb * 64 + (nf >> 1) * 32 + quad * 8 + (nf & 1) * 4;
          #pragma unroll
          for (int r = 0; r < 4; ++r)
            if (kc + r > qg) s[nf][r] = NEG;
        }
      }

      // P = exp2(S') (log2e pre-folded into Q); lane holds
      // P[q=ln][k = ks*32 + quad*8 + (hh*4+r)] == byte-exact A-fragment.
      v8bf pa[2];
      #pragma unroll
      for (int ks = 0; ks < 2; ++ks)
        #pragma unroll
        for (int hh = 0; hh < 2; ++hh)
          #pragma unroll
          for (int r = 0; r < 4; ++r)
            pa[ks][hh * 4 + r] = f2braw(exp2f(s[2 * ks + hh][r]));

      __builtin_amdgcn_s_setprio(1);
      lacc[mc] = MFMA16(pa[0], vone, lacc[mc]);  // row sums (same C layout)
      lacc[mc] = MFMA16(pa[1], vone, lacc[mc]);
      #pragma unroll
      for (int ks = 0; ks < 2; ++ks)
        #pragma unroll
        for (int dt = 0; dt < 4; ++dt)
          o[mc][dt] = MFMA16(pa[ks], vf[ks][dt], o[mc][dt]);
      __builtin_amdgcn_s_setprio(0);
    }
  }
  #undef STAGE

  // epilogue: normalize, store att[b*2048+q][h*64+d]; q = wrow+mc*16+quad*4+r
  #pragma unroll
  for (int mc = 0; mc < 2; ++mc) {
    v4f inv;
    #pragma unroll
    for (int r = 0; r < 4; ++r) inv[r] = 1.0f / lacc[mc][r];
    #pragma unroll
    for (int dt = 0; dt < 4; ++dt)
      #pragma unroll
      for (int r = 0; r < 4; ++r) {
        int m = b * 2048 + wrow + mc * 16 + quad * 4 + r;
        att[(size_t)m * 1024 + h * 64 + dt * 16 + ln] =
            f2b(o[mc][dt][r] * inv[r]);
      }
  }
}

// ---------------------------------------------------------------------------
// Kernel 3: output projection + bias, fp32 out. 128x64 tiles, BK=32,
// double-buffered, ONE barrier per k-step. grid (32 mt, 16 nt).
// ---------------------------------------------------------------------------
__global__ __launch_bounds__(256) void out_gemm_kernel(
    const bf16* __restrict__ att, const bf16* __restrict__ wot,
    const float* __restrict__ bo, float* __restrict__ out)
{
  __shared__ __align__(16) bf16 Ash[2][128][32];
  __shared__ __align__(16) bf16 Bsh[2][64][32];

  const int mt = blockIdx.x, nt = blockIdx.y;
  const int tid = threadIdx.x, w = tid >> 6, lane = tid & 63;
  const int ln = lane & 15, quad = lane >> 4;
  const int wm = w >> 1, wn = w & 1;
  const int m0 = mt * 128, n0 = nt * 64;

  const v4f vzero = {0.f, 0.f, 0.f, 0.f};
  v4f acc[4][2];
  #pragma unroll
  for (int mf = 0; mf < 4; ++mf)
    #pragma unroll
    for (int nf = 0; nf < 2; ++nf) acc[mf][nf] = vzero;

  const int srow = lane >> 2, sseg = (lane & 3) * 8;
  const bf16* ga = att + (size_t)(m0 + 32 * w + srow) * 1024 + sseg;
  const bf16* gb = wot + (size_t)(n0 + 16 * w + srow) * 1024 + sseg;

  {
    load16_lds(ga,             &Ash[0][32 * w][0]);
    load16_lds(ga + 16 * 1024, &Ash[0][32 * w + 16][0]);
    load16_lds(gb,             &Bsh[0][16 * w][0]);
  }

  for (int kt = 0; kt < 32; ++kt) {
    const int buf = kt & 1;
    __syncthreads();

    v8bf af[4], bfv[2];
    #pragma unroll
    for (int mf = 0; mf < 4; ++mf)
      af[mf] = *(const v8bf*)&Ash[buf][wm * 64 + mf * 16 + ln][quad * 8];
    #pragma unroll
    for (int nf = 0; nf < 2; ++nf)
      bfv[nf] = *(const v8bf*)&Bsh[buf][wn * 32 + nf * 16 + ln][quad * 8];

    if (kt < 31) {
      const int k0 = (kt + 1) * 32, nb = buf ^ 1;
      load16_lds(ga + k0,             &Ash[nb][32 * w][0]);
      load16_lds(ga + 16 * 1024 + k0, &Ash[nb][32 * w + 16][0]);
      load16_lds(gb + k0,             &Bsh[nb][16 * w][0]);
    }

    #pragma unroll
    for (int mf = 0; mf < 4; ++mf)
      #pragma unroll
      for (int nf = 0; nf < 2; ++nf)
        acc[mf][nf] = MFMA16(af[mf], bfv[nf], acc[mf][nf]);
  }

  #pragma unroll
  for (int nf = 0; nf < 2; ++nf) {
    int j = n0 + wn * 32 + nf * 16 + ln;
    float bias = bo[j];
    #pragma unroll
    for (int mf = 0; mf < 4; ++mf)
      #pragma unroll
      for (int r = 0; r < 4; ++r) {
        int m = m0 + wm * 64 + mf * 16 + quad * 4 + r;
        out[(size_t)m * 1024 + j] = acc[mf][nf][r] + bias;
      }
  }
}

extern "C" void kernel_launch(void* const* d_in, const int* in_sizes, int n_in,
                              void* d_out, int out_size, void* d_ws, size_t ws_size,
                              hipStream_t stream) {
  const float* x  = (const float*)d_in[0];
  const float* Wq = (const float*)d_in[1];
  const float* Wk = (const float*)d_in[2];
  const float* Wv = (const float*)d_in[3];
  const float* Wo = (const float*)d_in[4];
  const float* bo = (const float*)d_in[5];
  float* out = (float*)d_out;

  bf16* xb  = (bf16*)d_ws;
  bf16* wt  = xb + 4194304;
  bf16* wot = xb + 7340032;
  bf16* qkv = xb + 8388608;
  bf16* att = xb + 20971520;

  prep_kernel<<<6144, 256, 0, stream>>>(x, Wq, Wk, Wv, Wo, xb, wt, wot);
  qkv_gemm_kernel<<<dim3(32, 24), 256, 0, stream>>>(xb, wt, qkv);
  attn_kernel<<<1024, 128, 0, stream>>>(qkv, att);
  out_gemm_kernel<<<dim3(32, 16), 256, 0, stream>>>(att, wot, bo, out);
}

// Round 5
// 168.706 us; speedup vs baseline: 1.0551x; 1.0551x over previous
//
#include <hip/hip_runtime.h>
#include <hip/hip_bf16.h>

// MultiHead attention, MI355X/gfx950. fp32 in/out, bf16 MFMA internals.
// B=2, T=2048, C=1024, H=16, D=64.
// Round 12: attn = R8 per-wave shape (4 waves x 16 q-rows, 16KB K/V tile
// shared by 4 waves, single-__syncthreads dbuf) at DOUBLE residency:
// one 64-row chunk per block, grid 1024x256thr = 4 blocks/CU = 16 waves/CU
// (4/SIMD; R8 had 2/SIMD). Non-uniform trips (mt+1) balanced by a 4-phase
// mt table {31-r, 8+r, 23-r, r} over j=fid>>5: every CU's 4 resident
// blocks sum to exactly 66 trips and hold a long job from t=0.
// Softmax P->bf16 via v_cvt_pk_bf16_f32 inline asm (8 instrs vs ~80 scalar
// cast path) -- R11 counters showed cvt VALU was the dominant busy term.
// R9/R10/R11 lessons: wave count hides the stall; uniform/balanced load
// beats per-wave amortization; counted-vmcnt 3-buf regressed.
//
// ws layout (bf16 elems):
//   xb  [4096][1024]            @ 0          (x as bf16)
//   wt  [3][16][64][1024]       @ 4194304    (= fused Bt [3072][1024])
//   wot [1024][1024]            @ 7340032    (Wo transposed, bf16)
//   qkv Q,K:[h][b*2048+t][d] Vt:[h][b][d][t] @ 8388608  (Q pre-scaled log2e/32)
//   att [4096][1024]            @ 20971520
// total 25165824 elems = 48 MB

typedef __hip_bfloat16 bf16;
typedef __bf16 v8bf __attribute__((ext_vector_type(8)));
typedef float  v4f  __attribute__((ext_vector_type(4)));
typedef unsigned long long u64;
typedef unsigned int u32;

#define MFMA16(a, b, c) __builtin_amdgcn_mfma_f32_16x16x32_bf16((a), (b), (c), 0, 0, 0)

__device__ __forceinline__ bf16 f2b(float x) { return __float2bfloat16(x); }
__device__ __forceinline__ __bf16 f2braw(float x) {
  bf16 t = __float2bfloat16(x);
  return *reinterpret_cast<__bf16*>(&t);
}
__device__ __forceinline__ unsigned short f2bu(float x) {
  bf16 t = __float2bfloat16(x);
  return *reinterpret_cast<unsigned short*>(&t);
}

// async global->LDS, 16B per lane; LDS dest = wave-uniform base + lane*16.
__device__ __forceinline__ void load16_lds(const bf16* gptr, const bf16* lptr) {
  __builtin_amdgcn_global_load_lds(
      (const __attribute__((address_space(1))) u32*)gptr,
      (__attribute__((address_space(3))) u32*)lptr, 16, 0, 0);
}

// ---------------------------------------------------------------------------
// Fused prep: [0,2048) cvt_x | [2048,5120) Wq/Wk/Wv transpose | [5120,6144) Wo.
// ---------------------------------------------------------------------------
__global__ __launch_bounds__(256) void prep_kernel(
    const float* __restrict__ x,
    const float* __restrict__ Wq, const float* __restrict__ Wk,
    const float* __restrict__ Wv, const float* __restrict__ Wo,
    bf16* __restrict__ xb, bf16* __restrict__ wt, bf16* __restrict__ wot)
{
  __shared__ float Lt[32][33];
  const int bid = blockIdx.x, tid = threadIdx.x;

  if (bid < 2048) {                        // x fp32 -> bf16
    size_t i = ((size_t)bid * 256 + tid) * 8;
    float4 f0 = *(const float4*)(x + i);
    float4 f1 = *(const float4*)(x + i + 4);
    v8bf v;
    v[0] = f2braw(f0.x); v[1] = f2braw(f0.y); v[2] = f2braw(f0.z); v[3] = f2braw(f0.w);
    v[4] = f2braw(f1.x); v[5] = f2braw(f1.y); v[6] = f2braw(f1.z); v[7] = f2braw(f1.w);
    *(v8bf*)(xb + i) = v;
    return;
  }
  const int tx = tid & 31, ty = tid >> 5;
  if (bid < 5120) {                        // Wq/Wk/Wv [h][1024][64] -> wt [z][64][1024]
    const int idx = bid - 2048;
    const int z = idx >> 6, rem = idx & 63;
    const int p = z >> 4, h = z & 15;
    const float* ib = ((p == 0) ? Wq : (p == 1) ? Wk : Wv) + (size_t)h * 65536;
    bf16* ob = wt + (size_t)z * 65536;
    const int j0 = (rem & 1) * 32, i0 = (rem >> 1) * 32;
    #pragma unroll
    for (int r = 0; r < 4; ++r)
      Lt[ty + 8 * r][tx] = ib[(size_t)(i0 + ty + 8 * r) * 64 + j0 + tx];
    __syncthreads();
    #pragma unroll
    for (int r = 0; r < 4; ++r)
      ob[(size_t)(j0 + ty + 8 * r) * 1024 + i0 + tx] = f2b(Lt[tx][ty + 8 * r]);
  } else {                                 // Wo [1024][1024] -> wot transposed
    const int idx = bid - 5120;
    const int j0 = (idx & 31) * 32, i0 = (idx >> 5) * 32;
    #pragma unroll
    for (int r = 0; r < 4; ++r)
      Lt[ty + 8 * r][tx] = Wo[(size_t)(i0 + ty + 8 * r) * 1024 + j0 + tx];
    __syncthreads();
    #pragma unroll
    for (int r = 0; r < 4; ++r)
      wot[(size_t)(j0 + ty + 8 * r) * 1024 + i0 + tx] = f2b(Lt[tx][ty + 8 * r]);
  }
}

// ---------------------------------------------------------------------------
// Kernel 1: fused QKV GEMM, M=4096 x N=3072, K=1024. 128x128 tile, BK=32,
// double-buffered LDS, ONE barrier per k-step. grid (32 mt, 24 nt).
// Epilogue scatters Q,K ([h][m][d], Q*log2e/32) and V transposed
// ([h][b][d][t]).
// ---------------------------------------------------------------------------
__global__ __launch_bounds__(256) void qkv_gemm_kernel(
    const bf16* __restrict__ xb, const bf16* __restrict__ wt,
    bf16* __restrict__ qkv)
{
  __shared__ __align__(16) bf16 Ash[2][128][32];
  __shared__ __align__(16) bf16 Bsh[2][128][32];

  const int mt = blockIdx.x, nt = blockIdx.y;
  const int tid = threadIdx.x, w = tid >> 6, lane = tid & 63;
  const int ln = lane & 15, quad = lane >> 4;
  const int wm = w >> 1, wn = w & 1;
  const int m0 = mt * 128, n0 = nt * 128;

  const v4f vzero = {0.f, 0.f, 0.f, 0.f};
  v4f acc[4][4];
  #pragma unroll
  for (int mf = 0; mf < 4; ++mf)
    #pragma unroll
    for (int nf = 0; nf < 4; ++nf) acc[mf][nf] = vzero;

  const int srow = lane >> 2, sseg = (lane & 3) * 8;
  const bf16* ga = xb + (size_t)(m0 + 32 * w + srow) * 1024 + sseg;
  const bf16* gb = wt + (size_t)(n0 + 32 * w + srow) * 1024 + sseg;

  // prologue: stage k-step 0 into buf 0
  {
    load16_lds(ga,             &Ash[0][32 * w][0]);
    load16_lds(ga + 16 * 1024, &Ash[0][32 * w + 16][0]);
    load16_lds(gb,             &Bsh[0][32 * w][0]);
    load16_lds(gb + 16 * 1024, &Bsh[0][32 * w + 16][0]);
  }

  for (int kt = 0; kt < 32; ++kt) {
    const int buf = kt & 1;
    __syncthreads();                       // publishes buf (drains loads)

    v8bf af[4], bfv[4];
    #pragma unroll
    for (int mf = 0; mf < 4; ++mf)
      af[mf] = *(const v8bf*)&Ash[buf][wm * 64 + mf * 16 + ln][quad * 8];
    #pragma unroll
    for (int nf = 0; nf < 4; ++nf)
      bfv[nf] = *(const v8bf*)&Bsh[buf][wn * 64 + nf * 16 + ln][quad * 8];

    if (kt < 31) {                         // stage kt+1 into other buffer
      const int k0 = (kt + 1) * 32, nb = buf ^ 1;
      load16_lds(ga + k0,             &Ash[nb][32 * w][0]);
      load16_lds(ga + 16 * 1024 + k0, &Ash[nb][32 * w + 16][0]);
      load16_lds(gb + k0,             &Bsh[nb][32 * w][0]);
      load16_lds(gb + 16 * 1024 + k0, &Bsh[nb][32 * w + 16][0]);
    }

    #pragma unroll
    for (int mf = 0; mf < 4; ++mf)
      #pragma unroll
      for (int nf = 0; nf < 4; ++nf)
        acc[mf][nf] = MFMA16(af[mf], bfv[nf], acc[mf][nf]);
  }

  const int jcol0 = n0 + wn * 64;
  const int p = jcol0 >> 10;
  const int h = (jcol0 >> 6) & 15;
  // Q pre-scale: (1/sqrt(1024)) * log2(e), so attn can use exp2 directly.
  const float scale = (p == 0) ? 0.0450841149f : 1.0f;

  if (p < 2) {                               // Q, K: [h][m][d]
    bf16* base = qkv + (size_t)p * 4194304 + (size_t)h * 262144;
    #pragma unroll
    for (int mf = 0; mf < 4; ++mf)
      #pragma unroll
      for (int nf = 0; nf < 4; ++nf) {
        int d = nf * 16 + ln;
        #pragma unroll
        for (int r = 0; r < 4; ++r) {
          int m = m0 + wm * 64 + mf * 16 + quad * 4 + r;
          base[(size_t)m * 64 + d] = f2b(acc[mf][nf][r] * scale);
        }
      }
  } else {                                   // V transposed: [h][b][d][t]
    bf16* vb = qkv + (size_t)2 * 4194304 + (size_t)h * 262144;
    #pragma unroll
    for (int mf = 0; mf < 4; ++mf) {
      int mrow = m0 + wm * 64 + mf * 16 + quad * 4;
      int bi = mrow >> 11, t0 = mrow & 2047;
      #pragma unroll
      for (int nf = 0; nf < 4; ++nf) {
        int d = nf * 16 + ln;
        u64 pk = (u64)f2bu(acc[mf][nf][0]) |
                 ((u64)f2bu(acc[mf][nf][1]) << 16) |
                 ((u64)f2bu(acc[mf][nf][2]) << 32) |
                 ((u64)f2bu(acc[mf][nf][3]) << 48);
        *(u64*)(vb + (size_t)bi * 131072 + (size_t)d * 2048 + t0) = pk;
      }
    }
  }
}

// ---------------------------------------------------------------------------
// Kernel 2: causal flash attention, swapped-QK^T in-register softmax.
// Block = 4 waves x 16 q-rows = one 64-row chunk; trips = mt+1 k-tiles.
// grid 1024 x 256thr = 4 blocks/CU = 16 waves/CU (4/SIMD).
// mt from j=fid>>5 via 4-phase table {31-r, 8+r, 23-r, r}: each CU's 4
// resident blocks (j, j+8, j+16, j+24) have trips summing to exactly 66,
// with the longest job resident from t=0 (within-CU LPT).
// Single-__syncthreads dbuf (best measured schedule). K staged row-PERMUTED
// (kperm) so S^T = mfma(K,Q) lanes, after exp2, are byte-exact A-fragments
// for PV. K/V LDS XOR slot-swizzled via pre-swizzled global source addrs.
// P->bf16 via v_cvt_pk_bf16_f32 (2 elems/instr). Row-sum via mfma(pa,ones).
// grp = fid&31 so same-(b,h) blocks share an XCD.
// ---------------------------------------------------------------------------
__global__ __launch_bounds__(256, 4) void attn_kernel(
    const bf16* __restrict__ qkv, bf16* __restrict__ att)
{
  __shared__ __align__(16) bf16 Ksh[2][64][64];   // [buf][perm-row][d, slot-swz]
  __shared__ __align__(16) bf16 Vsh[2][64][64];   // [buf][d][t', slot-swz]

  const int fid = blockIdx.x;              // 0..1023
  const int j = fid >> 5;                  // 0..31
  const int jr = j & 7, jq = j >> 3;
  // 4-phase balanced mt table: {31-r, 8+r, 23-r, r}
  const int mt = (jq == 0) ? (31 - jr) : (jq == 1) ? (8 + jr)
               : (jq == 2) ? (23 - jr) : jr;
  const int grp = fid & 31;                // fid%8 == grp%8 -> same-grp same XCD
  const int b = grp >> 4, h = grp & 15;

  const int tid = threadIdx.x, w = tid >> 6, lane = tid & 63;
  const int ln = lane & 15, quad = lane >> 4;

  const bf16* qbase  = qkv + (size_t)h * 262144 + (size_t)b * 131072;
  const bf16* kbase  = qbase + 4194304;
  const bf16* vtbase = qbase + 8388608;    // [d][t], d-stride 2048

  // ---- staging lane constants (wave w stages LDS rows w*16..w*16+15) ----
  const int l8 = lane & 7, r8 = lane >> 3;
  const int slot = l8 ^ r8;                // swizzle: LDS[row][s] = G[row][s^(row&7)]
  const int p0 = w * 16 + r8, p1 = p0 + 8;
  // kperm(p): LDS row p holds K row (p&32) | ((p&12)<<1) | ((p&16)>>2) | (p&3)
  const int kp0 = (p0 & 32) | ((p0 & 12) << 1) | ((p0 & 16) >> 2) | (p0 & 3);
  const int kp1 = (p1 & 32) | ((p1 & 12) << 1) | ((p1 & 16) >> 2) | (p1 & 3);
  const bf16* gk0 = kbase + kp0 * 64 + slot * 8;
  const bf16* gk1 = kbase + kp1 * 64 + slot * 8;
  const bf16* gv0 = vtbase + p0 * 2048 + slot * 8;
  const bf16* gv1 = gv0 + 8 * 2048;

  // ---- fragment-read lane constants (element offsets into [64][64]) ----
  const int sw = ln & 7;
  const int c0 = ((quad    ) ^ sw) * 8;    // ks=0: global slot quad
  const int c1 = ((quad + 4) ^ sw) * 8;    // ks=1: global slot 4+quad
  const int rowoff = ln * 64;

  v8bf vone;
  {
    unsigned short u = 0x3F80;             // 1.0 bf16
    __bf16 e = *reinterpret_cast<__bf16*>(&u);
    #pragma unroll
    for (int jj = 0; jj < 8; ++jj) vone[jj] = e;
  }
  const v4f vzero = {0.f, 0.f, 0.f, 0.f};
  const float NEG = -30000.0f;

  #define STAGE(KB, BUF) {                                       \
    load16_lds(gk0 + (KB) * 4096, &Ksh[BUF][w * 16][0]);         \
    load16_lds(gk1 + (KB) * 4096, &Ksh[BUF][w * 16 + 8][0]);     \
    load16_lds(gv0 + (KB) * 64,   &Vsh[BUF][w * 16][0]);         \
    load16_lds(gv1 + (KB) * 64,   &Vsh[BUF][w * 16 + 8][0]); }

  const int wrow = mt * 64 + w * 16;       // wave's q rows: wrow..wrow+15
  const int qg = wrow + ln;                // this lane's q row (S^T col)

  // Q fragments (B-operand): Q[wrow+ln][ks*32 + quad*8 + j]
  v8bf aq[2];
  #pragma unroll
  for (int ks = 0; ks < 2; ++ks)
    aq[ks] = *(const v8bf*)(qbase + (size_t)(wrow + ln) * 64 + ks * 32 + quad * 8);

  v4f o[4], lacc;
  lacc = vzero;
  #pragma unroll
  for (int dt = 0; dt < 4; ++dt) o[dt] = vzero;

  STAGE(0, 0)

  const int kb_end = mt;
  for (int kb = 0; kb <= kb_end; ++kb) {
    const int buf = kb & 1;
    __syncthreads();                       // publishes buf (drains loads)

    v8bf kf[2][4], vf[2][4];
    const bf16* kr = &Ksh[buf][0][0];
    const bf16* vr = &Vsh[buf][0][0];
    #pragma unroll
    for (int nf = 0; nf < 4; ++nf) {
      kf[0][nf] = *(const v8bf*)(kr + nf * 1024 + rowoff + c0);
      kf[1][nf] = *(const v8bf*)(kr + nf * 1024 + rowoff + c1);
      vf[0][nf] = *(const v8bf*)(vr + nf * 1024 + rowoff + c0);
      vf[1][nf] = *(const v8bf*)(vr + nf * 1024 + rowoff + c1);
    }

    if (kb < kb_end) STAGE(kb + 1, buf ^ 1)

    // S^T = K . Q^T : D[m = perm'd k][n = q(ln)]
    __builtin_amdgcn_s_setprio(1);
    v4f s[4];
    #pragma unroll
    for (int nf = 0; nf < 4; ++nf) s[nf] = vzero;
    #pragma unroll
    for (int ks = 0; ks < 2; ++ks)
      #pragma unroll
      for (int nf = 0; nf < 4; ++nf)
        s[nf] = MFMA16(kf[ks][nf], aq[ks], s[nf]);
    __builtin_amdgcn_s_setprio(0);

    if (kb == kb_end) {                    // causal mask (diagonal tile)
      #pragma unroll
      for (int nf = 0; nf < 4; ++nf) {
        const int kc = kb * 64 + (nf >> 1) * 32 + quad * 8 + (nf & 1) * 4;
        #pragma unroll
        for (int r = 0; r < 4; ++r)
          if (kc + r > qg) s[nf][r] = NEG;
      }
    }

    // P = exp2(S') (log2e pre-folded into Q); lane holds
    // P[q=ln][k = ks*32 + quad*8 + (hh*4+r)] == byte-exact A-fragment.
    // bf16 pack via v_cvt_pk_bf16_f32: 2 elems/instr.
    float ex[4][4];
    #pragma unroll
    for (int nf = 0; nf < 4; ++nf)
      #pragma unroll
      for (int r = 0; r < 4; ++r)
        ex[nf][r] = exp2f(s[nf][r]);

    union { u32 w[4]; v8bf v; } pu[2];
    #pragma unroll
    for (int ks = 0; ks < 2; ++ks)
      #pragma unroll
      for (int hh = 0; hh < 2; ++hh)
        #pragma unroll
        for (int wi = 0; wi < 2; ++wi)
          asm("v_cvt_pk_bf16_f32 %0, %1, %2"
              : "=v"(pu[ks].w[hh * 2 + wi])
              : "v"(ex[2 * ks + hh][2 * wi]), "v"(ex[2 * ks + hh][2 * wi + 1]));

    __builtin_amdgcn_s_setprio(1);
    lacc = MFMA16(pu[0].v, vone, lacc);    // row sums (same C layout as o)
    lacc = MFMA16(pu[1].v, vone, lacc);
    #pragma unroll
    for (int ks = 0; ks < 2; ++ks)
      #pragma unroll
      for (int dt = 0; dt < 4; ++dt)
        o[dt] = MFMA16(pu[ks].v, vf[ks][dt], o[dt]);
    __builtin_amdgcn_s_setprio(0);
  }
  #undef STAGE

  // epilogue: normalize, store att[b*2048+q][h*64+d]; q = wrow+quad*4+r
  v4f inv;
  #pragma unroll
  for (int r = 0; r < 4; ++r) inv[r] = 1.0f / lacc[r];
  #pragma unroll
  for (int dt = 0; dt < 4; ++dt)
    #pragma unroll
    for (int r = 0; r < 4; ++r) {
      int m = b * 2048 + wrow + quad * 4 + r;
      att[(size_t)m * 1024 + h * 64 + dt * 16 + ln] = f2b(o[dt][r] * inv[r]);
    }
}

// ---------------------------------------------------------------------------
// Kernel 3: output projection + bias, fp32 out. 128x64 tiles, BK=32,
// double-buffered, ONE barrier per k-step. grid (32 mt, 16 nt).
// ---------------------------------------------------------------------------
__global__ __launch_bounds__(256) void out_gemm_kernel(
    const bf16* __restrict__ att, const bf16* __restrict__ wot,
    const float* __restrict__ bo, float* __restrict__ out)
{
  __shared__ __align__(16) bf16 Ash[2][128][32];
  __shared__ __align__(16) bf16 Bsh[2][64][32];

  const int mt = blockIdx.x, nt = blockIdx.y;
  const int tid = threadIdx.x, w = tid >> 6, lane = tid & 63;
  const int ln = lane & 15, quad = lane >> 4;
  const int wm = w >> 1, wn = w & 1;
  const int m0 = mt * 128, n0 = nt * 64;

  const v4f vzero = {0.f, 0.f, 0.f, 0.f};
  v4f acc[4][2];
  #pragma unroll
  for (int mf = 0; mf < 4; ++mf)
    #pragma unroll
    for (int nf = 0; nf < 2; ++nf) acc[mf][nf] = vzero;

  const int srow = lane >> 2, sseg = (lane & 3) * 8;
  const bf16* ga = att + (size_t)(m0 + 32 * w + srow) * 1024 + sseg;
  const bf16* gb = wot + (size_t)(n0 + 16 * w + srow) * 1024 + sseg;

  {
    load16_lds(ga,             &Ash[0][32 * w][0]);
    load16_lds(ga + 16 * 1024, &Ash[0][32 * w + 16][0]);
    load16_lds(gb,             &Bsh[0][16 * w][0]);
  }

  for (int kt = 0; kt < 32; ++kt) {
    const int buf = kt & 1;
    __syncthreads();

    v8bf af[4], bfv[2];
    #pragma unroll
    for (int mf = 0; mf < 4; ++mf)
      af[mf] = *(const v8bf*)&Ash[buf][wm * 64 + mf * 16 + ln][quad * 8];
    #pragma unroll
    for (int nf = 0; nf < 2; ++nf)
      bfv[nf] = *(const v8bf*)&Bsh[buf][wn * 32 + nf * 16 + ln][quad * 8];

    if (kt < 31) {
      const int k0 = (kt + 1) * 32, nb = buf ^ 1;
      load16_lds(ga + k0,             &Ash[nb][32 * w][0]);
      load16_lds(ga + 16 * 1024 + k0, &Ash[nb][32 * w + 16][0]);
      load16_lds(gb + k0,             &Bsh[nb][16 * w][0]);
    }

    #pragma unroll
    for (int mf = 0; mf < 4; ++mf)
      #pragma unroll
      for (int nf = 0; nf < 2; ++nf)
        acc[mf][nf] = MFMA16(af[mf], bfv[nf], acc[mf][nf]);
  }

  #pragma unroll
  for (int nf = 0; nf < 2; ++nf) {
    int j = n0 + wn * 32 + nf * 16 + ln;
    float bias = bo[j];
    #pragma unroll
    for (int mf = 0; mf < 4; ++mf)
      #pragma unroll
      for (int r = 0; r < 4; ++r) {
        int m = m0 + wm * 64 + mf * 16 + quad * 4 + r;
        out[(size_t)m * 1024 + j] = acc[mf][nf][r] + bias;
      }
  }
}

extern "C" void kernel_launch(void* const* d_in, const int* in_sizes, int n_in,
                              void* d_out, int out_size, void* d_ws, size_t ws_size,
                              hipStream_t stream) {
  const float* x  = (const float*)d_in[0];
  const float* Wq = (const float*)d_in[1];
  const float* Wk = (const float*)d_in[2];
  const float* Wv = (const float*)d_in[3];
  const float* Wo = (const float*)d_in[4];
  const float* bo = (const float*)d_in[5];
  float* out = (float*)d_out;

  bf16* xb  = (bf16*)d_ws;
  bf16* wt  = xb + 4194304;
  bf16* wot = xb + 7340032;
  bf16* qkv = xb + 8388608;
  bf16* att = xb + 20971520;

  prep_kernel<<<6144, 256, 0, stream>>>(x, Wq, Wk, Wv, Wo, xb, wt, wot);
  qkv_gemm_kernel<<<dim3(32, 24), 256, 0, stream>>>(xb, wt, qkv);
  attn_kernel<<<1024, 256, 0, stream>>>(qkv, att);
  out_gemm_kernel<<<dim3(32, 16), 256, 0, stream>>>(att, wot, bo, out);
}

// Round 6
// 164.307 us; speedup vs baseline: 1.0834x; 1.0268x over previous
//
#include <hip/hip_runtime.h>
#include <hip/hip_bf16.h>

// MultiHead attention, MI355X/gfx950. fp32 in/out, bf16 MFMA internals.
// B=2, T=2048, C=1024, H=16, D=64.
// Round 13: attn quadrant split. Waves own (q-half x kv-half) 32x32
// quadrants of each 64x64 block-tile: each wave reads only its 2 K-row
// groups + its kv-half of V = 8KB/wave-tile (was 16KB) -> block-tile LDS
// reads 64KB -> 32KB, total 1.08GB -> 540MB. R12 analysis: LDS port time
// (~17us/CU) was the occupancy-insensitive floor; R9/R11/R12 moved waves
// around without cutting it. kperm/swizzle/staging byte-identical to the
// verified R12 kernel (index restriction only). kv-half partials combined
// once per block via an 18.7KB scratch UNIONED over the dead K/V LDS
// (block LDS stays 32KB = 4 blocks/CU). Keeps: 4-phase balanced mt table,
// exp2+log2e-prescale, v_cvt_pk_bf16_f32, setprio, single-barrier dbuf.
//
// ws layout (bf16 elems):
//   xb  [4096][1024]            @ 0          (x as bf16)
//   wt  [3][16][64][1024]       @ 4194304    (= fused Bt [3072][1024])
//   wot [1024][1024]            @ 7340032    (Wo transposed, bf16)
//   qkv Q,K:[h][b*2048+t][d] Vt:[h][b][d][t] @ 8388608  (Q pre-scaled log2e/32)
//   att [4096][1024]            @ 20971520
// total 25165824 elems = 48 MB

typedef __hip_bfloat16 bf16;
typedef __bf16 v8bf __attribute__((ext_vector_type(8)));
typedef float  v4f  __attribute__((ext_vector_type(4)));
typedef unsigned long long u64;
typedef unsigned int u32;

#define MFMA16(a, b, c) __builtin_amdgcn_mfma_f32_16x16x32_bf16((a), (b), (c), 0, 0, 0)

__device__ __forceinline__ bf16 f2b(float x) { return __float2bfloat16(x); }
__device__ __forceinline__ __bf16 f2braw(float x) {
  bf16 t = __float2bfloat16(x);
  return *reinterpret_cast<__bf16*>(&t);
}
__device__ __forceinline__ unsigned short f2bu(float x) {
  bf16 t = __float2bfloat16(x);
  return *reinterpret_cast<unsigned short*>(&t);
}

// async global->LDS, 16B per lane; LDS dest = wave-uniform base + lane*16.
__device__ __forceinline__ void load16_lds(const bf16* gptr, const bf16* lptr) {
  __builtin_amdgcn_global_load_lds(
      (const __attribute__((address_space(1))) u32*)gptr,
      (__attribute__((address_space(3))) u32*)lptr, 16, 0, 0);
}

// ---------------------------------------------------------------------------
// Fused prep: [0,2048) cvt_x | [2048,5120) Wq/Wk/Wv transpose | [5120,6144) Wo.
// ---------------------------------------------------------------------------
__global__ __launch_bounds__(256) void prep_kernel(
    const float* __restrict__ x,
    const float* __restrict__ Wq, const float* __restrict__ Wk,
    const float* __restrict__ Wv, const float* __restrict__ Wo,
    bf16* __restrict__ xb, bf16* __restrict__ wt, bf16* __restrict__ wot)
{
  __shared__ float Lt[32][33];
  const int bid = blockIdx.x, tid = threadIdx.x;

  if (bid < 2048) {                        // x fp32 -> bf16
    size_t i = ((size_t)bid * 256 + tid) * 8;
    float4 f0 = *(const float4*)(x + i);
    float4 f1 = *(const float4*)(x + i + 4);
    v8bf v;
    v[0] = f2braw(f0.x); v[1] = f2braw(f0.y); v[2] = f2braw(f0.z); v[3] = f2braw(f0.w);
    v[4] = f2braw(f1.x); v[5] = f2braw(f1.y); v[6] = f2braw(f1.z); v[7] = f2braw(f1.w);
    *(v8bf*)(xb + i) = v;
    return;
  }
  const int tx = tid & 31, ty = tid >> 5;
  if (bid < 5120) {                        // Wq/Wk/Wv [h][1024][64] -> wt [z][64][1024]
    const int idx = bid - 2048;
    const int z = idx >> 6, rem = idx & 63;
    const int p = z >> 4, h = z & 15;
    const float* ib = ((p == 0) ? Wq : (p == 1) ? Wk : Wv) + (size_t)h * 65536;
    bf16* ob = wt + (size_t)z * 65536;
    const int j0 = (rem & 1) * 32, i0 = (rem >> 1) * 32;
    #pragma unroll
    for (int r = 0; r < 4; ++r)
      Lt[ty + 8 * r][tx] = ib[(size_t)(i0 + ty + 8 * r) * 64 + j0 + tx];
    __syncthreads();
    #pragma unroll
    for (int r = 0; r < 4; ++r)
      ob[(size_t)(j0 + ty + 8 * r) * 1024 + i0 + tx] = f2b(Lt[tx][ty + 8 * r]);
  } else {                                 // Wo [1024][1024] -> wot transposed
    const int idx = bid - 5120;
    const int j0 = (idx & 31) * 32, i0 = (idx >> 5) * 32;
    #pragma unroll
    for (int r = 0; r < 4; ++r)
      Lt[ty + 8 * r][tx] = Wo[(size_t)(i0 + ty + 8 * r) * 1024 + j0 + tx];
    __syncthreads();
    #pragma unroll
    for (int r = 0; r < 4; ++r)
      wot[(size_t)(j0 + ty + 8 * r) * 1024 + i0 + tx] = f2b(Lt[tx][ty + 8 * r]);
  }
}

// ---------------------------------------------------------------------------
// Kernel 1: fused QKV GEMM, M=4096 x N=3072, K=1024. 128x128 tile, BK=32,
// double-buffered LDS, ONE barrier per k-step. grid (32 mt, 24 nt).
// Epilogue scatters Q,K ([h][m][d], Q*log2e/32) and V transposed
// ([h][b][d][t]).
// ---------------------------------------------------------------------------
__global__ __launch_bounds__(256) void qkv_gemm_kernel(
    const bf16* __restrict__ xb, const bf16* __restrict__ wt,
    bf16* __restrict__ qkv)
{
  __shared__ __align__(16) bf16 Ash[2][128][32];
  __shared__ __align__(16) bf16 Bsh[2][128][32];

  const int mt = blockIdx.x, nt = blockIdx.y;
  const int tid = threadIdx.x, w = tid >> 6, lane = tid & 63;
  const int ln = lane & 15, quad = lane >> 4;
  const int wm = w >> 1, wn = w & 1;
  const int m0 = mt * 128, n0 = nt * 128;

  const v4f vzero = {0.f, 0.f, 0.f, 0.f};
  v4f acc[4][4];
  #pragma unroll
  for (int mf = 0; mf < 4; ++mf)
    #pragma unroll
    for (int nf = 0; nf < 4; ++nf) acc[mf][nf] = vzero;

  const int srow = lane >> 2, sseg = (lane & 3) * 8;
  const bf16* ga = xb + (size_t)(m0 + 32 * w + srow) * 1024 + sseg;
  const bf16* gb = wt + (size_t)(n0 + 32 * w + srow) * 1024 + sseg;

  // prologue: stage k-step 0 into buf 0
  {
    load16_lds(ga,             &Ash[0][32 * w][0]);
    load16_lds(ga + 16 * 1024, &Ash[0][32 * w + 16][0]);
    load16_lds(gb,             &Bsh[0][32 * w][0]);
    load16_lds(gb + 16 * 1024, &Bsh[0][32 * w + 16][0]);
  }

  for (int kt = 0; kt < 32; ++kt) {
    const int buf = kt & 1;
    __syncthreads();                       // publishes buf (drains loads)

    v8bf af[4], bfv[4];
    #pragma unroll
    for (int mf = 0; mf < 4; ++mf)
      af[mf] = *(const v8bf*)&Ash[buf][wm * 64 + mf * 16 + ln][quad * 8];
    #pragma unroll
    for (int nf = 0; nf < 4; ++nf)
      bfv[nf] = *(const v8bf*)&Bsh[buf][wn * 64 + nf * 16 + ln][quad * 8];

    if (kt < 31) {                         // stage kt+1 into other buffer
      const int k0 = (kt + 1) * 32, nb = buf ^ 1;
      load16_lds(ga + k0,             &Ash[nb][32 * w][0]);
      load16_lds(ga + 16 * 1024 + k0, &Ash[nb][32 * w + 16][0]);
      load16_lds(gb + k0,             &Bsh[nb][32 * w][0]);
      load16_lds(gb + 16 * 1024 + k0, &Bsh[nb][32 * w + 16][0]);
    }

    #pragma unroll
    for (int mf = 0; mf < 4; ++mf)
      #pragma unroll
      for (int nf = 0; nf < 4; ++nf)
        acc[mf][nf] = MFMA16(af[mf], bfv[nf], acc[mf][nf]);
  }

  const int jcol0 = n0 + wn * 64;
  const int p = jcol0 >> 10;
  const int h = (jcol0 >> 6) & 15;
  // Q pre-scale: (1/sqrt(1024)) * log2(e), so attn can use exp2 directly.
  const float scale = (p == 0) ? 0.0450841149f : 1.0f;

  if (p < 2) {                               // Q, K: [h][m][d]
    bf16* base = qkv + (size_t)p * 4194304 + (size_t)h * 262144;
    #pragma unroll
    for (int mf = 0; mf < 4; ++mf)
      #pragma unroll
      for (int nf = 0; nf < 4; ++nf) {
        int d = nf * 16 + ln;
        #pragma unroll
        for (int r = 0; r < 4; ++r) {
          int m = m0 + wm * 64 + mf * 16 + quad * 4 + r;
          base[(size_t)m * 64 + d] = f2b(acc[mf][nf][r] * scale);
        }
      }
  } else {                                   // V transposed: [h][b][d][t]
    bf16* vb = qkv + (size_t)2 * 4194304 + (size_t)h * 262144;
    #pragma unroll
    for (int mf = 0; mf < 4; ++mf) {
      int mrow = m0 + wm * 64 + mf * 16 + quad * 4;
      int bi = mrow >> 11, t0 = mrow & 2047;
      #pragma unroll
      for (int nf = 0; nf < 4; ++nf) {
        int d = nf * 16 + ln;
        u64 pk = (u64)f2bu(acc[mf][nf][0]) |
                 ((u64)f2bu(acc[mf][nf][1]) << 16) |
                 ((u64)f2bu(acc[mf][nf][2]) << 32) |
                 ((u64)f2bu(acc[mf][nf][3]) << 48);
        *(u64*)(vb + (size_t)bi * 131072 + (size_t)d * 2048 + t0) = pk;
      }
    }
  }
}

// ---------------------------------------------------------------------------
// Kernel 2: causal flash attention, swapped-QK^T in-register softmax,
// QUADRANT-SPLIT waves. Block = 4 waves, 64 q-rows, trips = mt+1 k-tiles.
// Wave w = (qh=w&1, kh=w>>1) computes the 32q x 32kv quadrant: reads only
// K rows nf in {2kh,2kh+1} (4KB) + V kv-half kh (4KB) per tile = 8KB/wave
// (was 16KB). kv-half partials (o, lacc) summed once per block through an
// LDS scratch unioned over the dead K/V buffers. Staging (kperm + slot
// swizzle) byte-identical to R12. grid 1024 x 256thr, 4 blocks/CU; mt via
// 4-phase balanced table {31-r, 8+r, 23-r, r} (per-CU trip sum = 66).
// ---------------------------------------------------------------------------
__global__ __launch_bounds__(256, 4) void attn_kernel(
    const bf16* __restrict__ qkv, bf16* __restrict__ att)
{
  union ShU {
    struct { bf16 K[2][64][64]; bf16 V[2][64][64]; } t;   // 32 KB tiles
    struct { float O[2][64][36]; float L[2][36]; } c;     // 18.7 KB combine
  };
  __shared__ __align__(16) ShU sh;

  const int fid = blockIdx.x;              // 0..1023
  const int j = fid >> 5;                  // 0..31
  const int jr = j & 7, jq = j >> 3;
  // 4-phase balanced mt table: {31-r, 8+r, 23-r, r}
  const int mt = (jq == 0) ? (31 - jr) : (jq == 1) ? (8 + jr)
               : (jq == 2) ? (23 - jr) : jr;
  const int grp = fid & 31;                // fid%8 == grp%8 -> same-grp same XCD
  const int b = grp >> 4, h = grp & 15;

  const int tid = threadIdx.x, w = tid >> 6, lane = tid & 63;
  const int ln = lane & 15, quad = lane >> 4;
  const int qh = w & 1, kh = w >> 1;       // quadrant ownership

  const bf16* qbase  = qkv + (size_t)h * 262144 + (size_t)b * 131072;
  const bf16* kbase  = qbase + 4194304;
  const bf16* vtbase = qbase + 8388608;    // [d][t], d-stride 2048

  // ---- staging lane constants (wave w stages LDS rows w*16..w*16+15) ----
  const int l8 = lane & 7, r8 = lane >> 3;
  const int slot = l8 ^ r8;                // swizzle: LDS[row][s] = G[row][s^(row&7)]
  const int p0 = w * 16 + r8, p1 = p0 + 8;
  // kperm(p): LDS row p holds K row (p&32) | ((p&12)<<1) | ((p&16)>>2) | (p&3)
  const int kp0 = (p0 & 32) | ((p0 & 12) << 1) | ((p0 & 16) >> 2) | (p0 & 3);
  const int kp1 = (p1 & 32) | ((p1 & 12) << 1) | ((p1 & 16) >> 2) | (p1 & 3);
  const bf16* gk0 = kbase + kp0 * 64 + slot * 8;
  const bf16* gk1 = kbase + kp1 * 64 + slot * 8;
  const bf16* gv0 = vtbase + p0 * 2048 + slot * 8;
  const bf16* gv1 = gv0 + 8 * 2048;

  // ---- fragment-read lane constants (element offsets into [64][64]) ----
  const int sw = ln & 7;
  const int cc0 = ((quad    ) ^ sw) * 8;   // granule for d/kv half 0
  const int cc1 = ((quad + 4) ^ sw) * 8;   // granule for d/kv half 1
  const int cck = kh ? cc1 : cc0;          // V col granule for this kv-half
  // K rows for this kv-half: (2kh+nfl)*16 + ln
  const int krow0 = (kh * 32 + ln) * 64;   // nfl=0 row offset (elems)
  const int krow1 = krow0 + 16 * 64;       // nfl=1

  v8bf vone;
  {
    unsigned short u = 0x3F80;             // 1.0 bf16
    __bf16 e = *reinterpret_cast<__bf16*>(&u);
    #pragma unroll
    for (int jj = 0; jj < 8; ++jj) vone[jj] = e;
  }
  const v4f vzero = {0.f, 0.f, 0.f, 0.f};
  const float NEG = -30000.0f;

  #define STAGE(KB, BUF) {                                       \
    load16_lds(gk0 + (KB) * 4096, &sh.t.K[BUF][w * 16][0]);      \
    load16_lds(gk1 + (KB) * 4096, &sh.t.K[BUF][w * 16 + 8][0]);  \
    load16_lds(gv0 + (KB) * 64,   &sh.t.V[BUF][w * 16][0]);      \
    load16_lds(gv1 + (KB) * 64,   &sh.t.V[BUF][w * 16 + 8][0]); }

  const int row0 = mt * 64;
  const int qrow = row0 + qh * 32;         // wave's q rows: qrow..qrow+31

  // Q fragments (B-operand): Q[qrow+mc*16+ln][ks*32 + quad*8 + j]
  v8bf aq[2][2];
  #pragma unroll
  for (int mc = 0; mc < 2; ++mc)
    #pragma unroll
    for (int ks = 0; ks < 2; ++ks)
      aq[mc][ks] = *(const v8bf*)(qbase +
          (size_t)(qrow + mc * 16 + ln) * 64 + ks * 32 + quad * 8);

  v4f o[2][4], lacc[2];
  #pragma unroll
  for (int mc = 0; mc < 2; ++mc) {
    lacc[mc] = vzero;
    #pragma unroll
    for (int dt = 0; dt < 4; ++dt) o[mc][dt] = vzero;
  }

  STAGE(0, 0)

  const int kb_end = mt;
  for (int kb = 0; kb <= kb_end; ++kb) {
    const int buf = kb & 1;
    __syncthreads();                       // publishes buf (drains loads)

    // this wave's K quadrant (2 nf groups x 2 d-halves) + V kv-half
    v8bf kf[2][2], vf[4];
    const bf16* kr = &sh.t.K[buf][0][0];
    const bf16* vr = &sh.t.V[buf][0][0];
    kf[0][0] = *(const v8bf*)(kr + krow0 + cc0);
    kf[1][0] = *(const v8bf*)(kr + krow0 + cc1);
    kf[0][1] = *(const v8bf*)(kr + krow1 + cc0);
    kf[1][1] = *(const v8bf*)(kr + krow1 + cc1);
    #pragma unroll
    for (int dt = 0; dt < 4; ++dt)
      vf[dt] = *(const v8bf*)(vr + (dt * 16 + ln) * 64 + cck);

    if (kb < kb_end) STAGE(kb + 1, buf ^ 1)

    #pragma unroll
    for (int mc = 0; mc < 2; ++mc) {
      // S^T quadrant: D[m = perm'd kv (this half)][n = q(ln)]
      __builtin_amdgcn_s_setprio(1);
      v4f s[2];
      s[0] = vzero; s[1] = vzero;
      #pragma unroll
      for (int ks = 0; ks < 2; ++ks)
        #pragma unroll
        for (int nfl = 0; nfl < 2; ++nfl)
          s[nfl] = MFMA16(kf[ks][nfl], aq[mc][ks], s[nfl]);
      __builtin_amdgcn_s_setprio(0);

      const int qg = qrow + mc * 16 + ln;
      if (kb == kb_end) {                  // causal mask (diagonal tile)
        #pragma unroll
        for (int nfl = 0; nfl < 2; ++nfl) {
          const int kc = kb * 64 + kh * 32 + quad * 8 + nfl * 4;
          #pragma unroll
          for (int r = 0; r < 4; ++r)
            if (kc + r > qg) s[nfl][r] = NEG;
        }
      }

      // P = exp2(S'); pa is the byte-exact K32 A-fragment for this kv-half
      float ex[2][4];
      #pragma unroll
      for (int nfl = 0; nfl < 2; ++nfl)
        #pragma unroll
        for (int r = 0; r < 4; ++r)
          ex[nfl][r] = exp2f(s[nfl][r]);

      union { u32 uw[4]; v8bf v; } pu;
      #pragma unroll
      for (int nfl = 0; nfl < 2; ++nfl)
        #pragma unroll
        for (int wi = 0; wi < 2; ++wi)
          asm("v_cvt_pk_bf16_f32 %0, %1, %2"
              : "=v"(pu.uw[nfl * 2 + wi])
              : "v"(ex[nfl][2 * wi]), "v"(ex[nfl][2 * wi + 1]));

      __builtin_amdgcn_s_setprio(1);
      lacc[mc] = MFMA16(pu.v, vone, lacc[mc]);   // partial row sums
      #pragma unroll
      for (int dt = 0; dt < 4; ++dt)
        o[mc][dt] = MFMA16(pu.v, vf[dt], o[mc][dt]);
      __builtin_amdgcn_s_setprio(0);
    }
  }
  #undef STAGE

  // ---- combine kv-half partials (kh=1 -> LDS, kh=0 adds) & epilogue ----
  __syncthreads();                         // all tile reads done; t is dead
  if (kh == 1) {
    #pragma unroll
    for (int mc = 0; mc < 2; ++mc) {
      #pragma unroll
      for (int dt = 0; dt < 4; ++dt)
        *(v4f*)&sh.c.O[qh][dt * 16 + ln][mc * 16 + quad * 4] = o[mc][dt];
      if (ln == 0)
        *(v4f*)&sh.c.L[qh][mc * 16 + quad * 4] = lacc[mc];
    }
  }
  __syncthreads();
  if (kh == 0) {
    #pragma unroll
    for (int mc = 0; mc < 2; ++mc) {
      v4f pl = *(const v4f*)&sh.c.L[qh][mc * 16 + quad * 4];
      v4f inv;
      #pragma unroll
      for (int r = 0; r < 4; ++r) inv[r] = 1.0f / (lacc[mc][r] + pl[r]);
      #pragma unroll
      for (int dt = 0; dt < 4; ++dt) {
        v4f po = *(const v4f*)&sh.c.O[qh][dt * 16 + ln][mc * 16 + quad * 4];
        #pragma unroll
        for (int r = 0; r < 4; ++r) {
          int m = b * 2048 + qrow + mc * 16 + quad * 4 + r;
          att[(size_t)m * 1024 + h * 64 + dt * 16 + ln] =
              f2b((o[mc][dt][r] + po[r]) * inv[r]);
        }
      }
    }
  }
}

// ---------------------------------------------------------------------------
// Kernel 3: output projection + bias, fp32 out. 128x64 tiles, BK=32,
// double-buffered, ONE barrier per k-step. grid (32 mt, 16 nt).
// ---------------------------------------------------------------------------
__global__ __launch_bounds__(256) void out_gemm_kernel(
    const bf16* __restrict__ att, const bf16* __restrict__ wot,
    const float* __restrict__ bo, float* __restrict__ out)
{
  __shared__ __align__(16) bf16 Ash[2][128][32];
  __shared__ __align__(16) bf16 Bsh[2][64][32];

  const int mt = blockIdx.x, nt = blockIdx.y;
  const int tid = threadIdx.x, w = tid >> 6, lane = tid & 63;
  const int ln = lane & 15, quad = lane >> 4;
  const int wm = w >> 1, wn = w & 1;
  const int m0 = mt * 128, n0 = nt * 64;

  const v4f vzero = {0.f, 0.f, 0.f, 0.f};
  v4f acc[4][2];
  #pragma unroll
  for (int mf = 0; mf < 4; ++mf)
    #pragma unroll
    for (int nf = 0; nf < 2; ++nf) acc[mf][nf] = vzero;

  const int srow = lane >> 2, sseg = (lane & 3) * 8;
  const bf16* ga = att + (size_t)(m0 + 32 * w + srow) * 1024 + sseg;
  const bf16* gb = wot + (size_t)(n0 + 16 * w + srow) * 1024 + sseg;

  {
    load16_lds(ga,             &Ash[0][32 * w][0]);
    load16_lds(ga + 16 * 1024, &Ash[0][32 * w + 16][0]);
    load16_lds(gb,             &Bsh[0][16 * w][0]);
  }

  for (int kt = 0; kt < 32; ++kt) {
    const int buf = kt & 1;
    __syncthreads();

    v8bf af[4], bfv[2];
    #pragma unroll
    for (int mf = 0; mf < 4; ++mf)
      af[mf] = *(const v8bf*)&Ash[buf][wm * 64 + mf * 16 + ln][quad * 8];
    #pragma unroll
    for (int nf = 0; nf < 2; ++nf)
      bfv[nf] = *(const v8bf*)&Bsh[buf][wn * 32 + nf * 16 + ln][quad * 8];

    if (kt < 31) {
      const int k0 = (kt + 1) * 32, nb = buf ^ 1;
      load16_lds(ga + k0,             &Ash[nb][32 * w][0]);
      load16_lds(ga + 16 * 1024 + k0, &Ash[nb][32 * w + 16][0]);
      load16_lds(gb + k0,             &Bsh[nb][16 * w][0]);
    }

    #pragma unroll
    for (int mf = 0; mf < 4; ++mf)
      #pragma unroll
      for (int nf = 0; nf < 2; ++nf)
        acc[mf][nf] = MFMA16(af[mf], bfv[nf], acc[mf][nf]);
  }

  #pragma unroll
  for (int nf = 0; nf < 2; ++nf) {
    int j = n0 + wn * 32 + nf * 16 + ln;
    float bias = bo[j];
    #pragma unroll
    for (int mf = 0; mf < 4; ++mf)
      #pragma unroll
      for (int r = 0; r < 4; ++r) {
        int m = m0 + wm * 64 + mf * 16 + quad * 4 + r;
        out[(size_t)m * 1024 + j] = acc[mf][nf][r] + bias;
      }
  }
}

extern "C" void kernel_launch(void* const* d_in, const int* in_sizes, int n_in,
                              void* d_out, int out_size, void* d_ws, size_t ws_size,
                              hipStream_t stream) {
  const float* x  = (const float*)d_in[0];
  const float* Wq = (const float*)d_in[1];
  const float* Wk = (const float*)d_in[2];
  const float* Wv = (const float*)d_in[3];
  const float* Wo = (const float*)d_in[4];
  const float* bo = (const float*)d_in[5];
  float* out = (float*)d_out;

  bf16* xb  = (bf16*)d_ws;
  bf16* wt  = xb + 4194304;
  bf16* wot = xb + 7340032;
  bf16* qkv = xb + 8388608;
  bf16* att = xb + 20971520;

  prep_kernel<<<6144, 256, 0, stream>>>(x, Wq, Wk, Wv, Wo, xb, wt, wot);
  qkv_gemm_kernel<<<dim3(32, 24), 256, 0, stream>>>(xb, wt, qkv);
  attn_kernel<<<1024, 256, 0, stream>>>(qkv, att);
  out_gemm_kernel<<<dim3(32, 16), 256, 0, stream>>>(att, wot, bo, out);
}